// Round 1
// baseline (571.118 us; speedup 1.0000x reference)
//
#include <hip/hip_runtime.h>
#include <hip/hip_bf16.h>
#include <cstdint>
#include <cstddef>

typedef __bf16 bf16_t;
typedef __bf16 bf16x4 __attribute__((ext_vector_type(4)));
typedef __bf16 bf16x8 __attribute__((ext_vector_type(8)));
typedef float f32x4 __attribute__((ext_vector_type(4)));

typedef __attribute__((address_space(1))) void as1_void_t;
typedef __attribute__((address_space(3))) void as3_void_t;

__device__ __forceinline__ void gload_lds16(const bf16_t* g, bf16_t* l) {
  __builtin_amdgcn_global_load_lds((as1_void_t*)g, (as3_void_t*)l, 16, 0, 0);
}

// ---------------------------------------------------------------------------
// Prep: cast x to bf16; cast+transpose weights (Wt[n][k] = W[k][n]) to bf16.
// ---------------------------------------------------------------------------
__global__ __launch_bounds__(256) void prep_k(
    const float* __restrict__ x,
    const float* __restrict__ wq, const float* __restrict__ wk,
    const float* __restrict__ wv, const float* __restrict__ wo,
    bf16_t* __restrict__ xb, bf16_t* __restrict__ wqt,
    bf16_t* __restrict__ wkt, bf16_t* __restrict__ wvt, bf16_t* __restrict__ wot)
{
  const int stride = gridDim.x * blockDim.x;
  const int tid = blockIdx.x * blockDim.x + threadIdx.x;
  const int NX4 = (8192 * 1024) / 4;
  for (int i = tid; i < NX4; i += stride) {
    float4 v = ((const float4*)x)[i];
    bf16x4 o;
    o[0] = (bf16_t)v.x; o[1] = (bf16_t)v.y; o[2] = (bf16_t)v.z; o[3] = (bf16_t)v.w;
    ((bf16x4*)xb)[i] = o;
  }
  const int NW = 1024 * 1024;
  for (int i = tid; i < NW; i += stride) {
    int k = i >> 10, n = i & 1023;
    int t = n * 1024 + k;
    wqt[t] = (bf16_t)wq[i];
    wkt[t] = (bf16_t)wk[i];
    wvt[t] = (bf16_t)wv[i];
    wot[t] = (bf16_t)wo[i];
  }
}

// ---------------------------------------------------------------------------
// GEMM: C[M=8192][N=1024] = A[M][K=1024] * Wt[N][K]^T  (both K-contiguous bf16)
// 128x128 tile, BK=64, 4 waves (2x2), each wave 64x64 = 4x4 MFMA tiles.
// LDS chunk-XOR swizzle: LDS pos (row, c) holds global chunk c^(row&7);
// staging keeps LDS dest linear and pre-swizzles the GLOBAL source (rule #21).
// MODE 0: bf16 headsplit [B,H,S,64] (*oscale after bias)   (Q, K)
// MODE 1: bf16 per-head transposed [B,H,64,S]              (V)
// MODE 2: fp32 row-major [M][N]                            (final out)
// ---------------------------------------------------------------------------
constexpr int BM = 128, BN = 128, BK = 64;

template <int MODE>
__global__ __launch_bounds__(256) void gemm_k(
    const bf16_t* __restrict__ A, const bf16_t* __restrict__ Bt,
    const float* __restrict__ bias, void* __restrict__ outp, float oscale)
{
  constexpr int K = 1024;
  __shared__ bf16_t a_lds[BM * BK];
  __shared__ bf16_t b_lds[BN * BK];
  const int tid = threadIdx.x;
  const int l = tid & 63;
  const int wv = tid >> 6;
  const int wr = wv >> 1, wc = wv & 1;
  const int lr = l & 15, lg = l >> 4;
  const int bm = blockIdx.x * BM;
  const int bn = blockIdx.y * BN;

  f32x4 acc[4][4] = {};

  const int srow = tid >> 3;        // staging row (advances by 32 per it)
  const int scc = tid & 7;          // staging chunk (linear LDS position)

  for (int k0 = 0; k0 < K; k0 += BK) {
    __syncthreads();
#pragma unroll
    for (int it = 0; it < 4; ++it) {
      int row = srow + it * 32;
      int gk = (scc ^ (row & 7)) * 8;  // inverse-swizzled global source chunk
      gload_lds16(A + (size_t)(bm + row) * K + k0 + gk, a_lds + row * BK + scc * 8);
      gload_lds16(Bt + (size_t)(bn + row) * K + k0 + gk, b_lds + row * BK + scc * 8);
    }
    __syncthreads();
#pragma unroll
    for (int kk = 0; kk < 2; ++kk) {
      bf16x8 af[4], bfr[4];
#pragma unroll
      for (int m = 0; m < 4; ++m) {
        int row = wr * 64 + m * 16 + lr;
        int ch = (kk * 4 + lg) ^ (row & 7);  // swizzled read chunk
        af[m] = *(const bf16x8*)&a_lds[row * BK + ch * 8];
      }
#pragma unroll
      for (int n = 0; n < 4; ++n) {
        int row = wc * 64 + n * 16 + lr;
        int ch = (kk * 4 + lg) ^ (row & 7);
        bfr[n] = *(const bf16x8*)&b_lds[row * BK + ch * 8];
      }
#pragma unroll
      for (int m = 0; m < 4; ++m)
#pragma unroll
        for (int n = 0; n < 4; ++n)
          acc[m][n] = __builtin_amdgcn_mfma_f32_16x16x32_bf16(af[m], bfr[n], acc[m][n], 0, 0, 0);
    }
  }

#pragma unroll
  for (int m = 0; m < 4; ++m) {
#pragma unroll
    for (int n = 0; n < 4; ++n) {
#pragma unroll
      for (int r = 0; r < 4; ++r) {
        int row = bm + wr * 64 + m * 16 + lg * 4 + r;   // D row = (l>>4)*4+r
        int col = bn + wc * 64 + n * 16 + lr;           // D col = l&15
        float v = acc[m][n][r] + bias[col];
        if constexpr (MODE == 0) {
          ((bf16_t*)outp)[((size_t)((row >> 11) * 16 + (col >> 6)) * 2048 + (row & 2047)) * 64 + (col & 63)] =
              (bf16_t)(v * oscale);
        } else if constexpr (MODE == 1) {
          ((bf16_t*)outp)[((size_t)((row >> 11) * 16 + (col >> 6)) * 64 + (col & 63)) * 2048 + (row & 2047)] =
              (bf16_t)v;
        } else {
          ((float*)outp)[(size_t)row * 1024 + col] = v;
        }
      }
    }
  }
}

// ---------------------------------------------------------------------------
// Causal flash attention. Q pre-scaled by 1/8. 4 waves/block, wave = 16 q rows.
// KVBLK = 32. Q [BH][S][64], K [BH][S][64], V transposed [BH][64][S], all bf16.
// Output: bf16 row-major [8192][1024].
// ---------------------------------------------------------------------------
__global__ __launch_bounds__(256) void attn_k(
    const bf16_t* __restrict__ Q, const bf16_t* __restrict__ Kmat,
    const bf16_t* __restrict__ Vt, bf16_t* __restrict__ O)
{
  const int S = 2048, HD = 64;
  const int bh = blockIdx.y;
  const int q0 = blockIdx.x * 64;
  const int tid = threadIdx.x;
  const int l = tid & 63, wv = tid >> 6;
  const int lr = l & 15, lg = l >> 4;
  const int qb = q0 + wv * 16;

  __shared__ bf16_t p_lds[4][16 * 32];

  const bf16_t* Qh = Q + (size_t)bh * S * HD;
  const bf16_t* Kh = Kmat + (size_t)bh * S * HD;
  const bf16_t* Vh = Vt + (size_t)bh * HD * S;

  bf16x8 qf0 = *(const bf16x8*)&Qh[(size_t)(qb + lr) * HD + lg * 8];
  bf16x8 qf1 = *(const bf16x8*)&Qh[(size_t)(qb + lr) * HD + 32 + lg * 8];

  float mst[4], lst[4];
  f32x4 oacc[4];
#pragma unroll
  for (int r = 0; r < 4; ++r) { mst[r] = -1e30f; lst[r] = 0.f; }
#pragma unroll
  for (int n = 0; n < 4; ++n) oacc[n] = f32x4{0.f, 0.f, 0.f, 0.f};

  const int kv_end = qb + 16;
  for (int kvb = 0; kvb < kv_end; kvb += 32) {
    // ---- scores S[16q x 32kv] = Q . K^T (2 n-tiles x 2 k-slices) ----
    f32x4 sj[2];
#pragma unroll
    for (int j = 0; j < 2; ++j) {
      bf16x8 kf0 = *(const bf16x8*)&Kh[(size_t)(kvb + j * 16 + lr) * HD + lg * 8];
      bf16x8 kf1 = *(const bf16x8*)&Kh[(size_t)(kvb + j * 16 + lr) * HD + 32 + lg * 8];
      f32x4 z = {0.f, 0.f, 0.f, 0.f};
      z = __builtin_amdgcn_mfma_f32_16x16x32_bf16(qf0, kf0, z, 0, 0, 0);
      z = __builtin_amdgcn_mfma_f32_16x16x32_bf16(qf1, kf1, z, 0, 0, 0);
      sj[j] = z;
    }
    // ---- causal mask (only tiles touching/over the diagonal) ----
    if (kvb + 31 > qb) {
#pragma unroll
      for (int j = 0; j < 2; ++j)
#pragma unroll
        for (int r = 0; r < 4; ++r) {
          int q = qb + lg * 4 + r;
          int kv = kvb + j * 16 + lr;
          if (kv > q) sj[j][r] = -1e30f;
        }
    }
    // ---- online softmax (row = 16 lanes of a group, xor 1,2,4,8) ----
    float alpha[4], p0[4], p1[4];
#pragma unroll
    for (int r = 0; r < 4; ++r) {
      float v = fmaxf(sj[0][r], sj[1][r]);
      v = fmaxf(v, __shfl_xor(v, 1));
      v = fmaxf(v, __shfl_xor(v, 2));
      v = fmaxf(v, __shfl_xor(v, 4));
      v = fmaxf(v, __shfl_xor(v, 8));
      float mnew = fmaxf(mst[r], v);
      alpha[r] = __expf(mst[r] - mnew);
      p0[r] = __expf(sj[0][r] - mnew);
      p1[r] = __expf(sj[1][r] - mnew);
      float s = p0[r] + p1[r];
      s += __shfl_xor(s, 1);
      s += __shfl_xor(s, 2);
      s += __shfl_xor(s, 4);
      s += __shfl_xor(s, 8);
      lst[r] = lst[r] * alpha[r] + s;
      mst[r] = mnew;
    }
#pragma unroll
    for (int n = 0; n < 4; ++n) {
      oacc[n][0] *= alpha[0]; oacc[n][1] *= alpha[1];
      oacc[n][2] *= alpha[2]; oacc[n][3] *= alpha[3];
    }
    // ---- P (D-layout) -> LDS -> A-fragment layout, 4-chunk XOR swizzle ----
#pragma unroll
    for (int r = 0; r < 4; ++r) {
      p_lds[wv][(lg * 4 + r) * 32 + ((0 * 16 + lr) ^ (r << 3))] = (bf16_t)p0[r];
      p_lds[wv][(lg * 4 + r) * 32 + ((1 * 16 + lr) ^ (r << 3))] = (bf16_t)p1[r];
    }
    bf16x8 pa = *(const bf16x8*)&p_lds[wv][lr * 32 + ((lg ^ (lr & 3)) * 8)];
    // ---- O += P . V  (V^T layout: contiguous along kv) ----
#pragma unroll
    for (int n = 0; n < 4; ++n) {
      bf16x8 vf = *(const bf16x8*)&Vh[(size_t)(n * 16 + lr) * S + kvb + lg * 8];
      oacc[n] = __builtin_amdgcn_mfma_f32_16x16x32_bf16(pa, vf, oacc[n], 0, 0, 0);
    }
  }
  // ---- epilogue: normalize, write bf16 row-major [8192][1024] ----
  const int b = bh >> 4, h = bh & 15;
#pragma unroll
  for (int r = 0; r < 4; ++r) {
    float inv = 1.0f / lst[r];
    int row = b * 2048 + qb + lg * 4 + r;
#pragma unroll
    for (int n = 0; n < 4; ++n) {
      int col = h * 64 + n * 16 + lr;
      O[(size_t)row * 1024 + col] = (bf16_t)(oacc[n][r] * inv);
    }
  }
}

// ---------------------------------------------------------------------------
extern "C" void kernel_launch(void* const* d_in, const int* in_sizes, int n_in,
                              void* d_out, int out_size, void* d_ws, size_t ws_size,
                              hipStream_t stream)
{
  (void)in_sizes; (void)n_in; (void)out_size; (void)ws_size;
  const float* x  = (const float*)d_in[0];
  const float* Wq = (const float*)d_in[1];
  const float* bq = (const float*)d_in[2];
  const float* Wk = (const float*)d_in[3];
  const float* bk = (const float*)d_in[4];
  const float* Wv = (const float*)d_in[5];
  const float* bv = (const float*)d_in[6];
  const float* Wo = (const float*)d_in[7];
  const float* bo = (const float*)d_in[8];

  char* ws = (char*)d_ws;
  bf16_t* xb   = (bf16_t*)(ws);                       // 16MB; reused as attn-out
  bf16_t* wqt  = (bf16_t*)(ws + (size_t)(16u << 20));
  bf16_t* wkt  = (bf16_t*)(ws + (size_t)(18u << 20));
  bf16_t* wvt  = (bf16_t*)(ws + (size_t)(20u << 20));
  bf16_t* wot  = (bf16_t*)(ws + (size_t)(22u << 20));
  bf16_t* qws  = (bf16_t*)(ws + (size_t)(24u << 20));
  bf16_t* kws  = (bf16_t*)(ws + (size_t)(40u << 20));
  bf16_t* vtws = (bf16_t*)(ws + (size_t)(56u << 20));

  prep_k<<<2048, 256, 0, stream>>>(x, Wq, Wk, Wv, Wo, xb, wqt, wkt, wvt, wot);

  dim3 gg(8192 / BM, 1024 / BN);
  gemm_k<0><<<gg, 256, 0, stream>>>(xb, wqt, bq, qws, 0.125f);   // Q (scale folded)
  gemm_k<0><<<gg, 256, 0, stream>>>(xb, wkt, bk, kws, 1.0f);     // K
  gemm_k<1><<<gg, 256, 0, stream>>>(xb, wvt, bv, vtws, 1.0f);    // V^T per head

  attn_k<<<dim3(32, 64), 256, 0, stream>>>(qws, kws, vtws, xb);  // out -> xb

  gemm_k<2><<<gg, 256, 0, stream>>>(xb, wot, bo, d_out, 1.0f);   // final, fp32
}

// Round 2
// 298.945 us; speedup vs baseline: 1.9104x; 1.9104x over previous
//
#include <hip/hip_runtime.h>
#include <hip/hip_bf16.h>
#include <cstdint>
#include <cstddef>

typedef __bf16 bf16_t;
typedef __bf16 bf16x4 __attribute__((ext_vector_type(4)));
typedef __bf16 bf16x8 __attribute__((ext_vector_type(8)));
typedef float f32x4 __attribute__((ext_vector_type(4)));
typedef float f32x16 __attribute__((ext_vector_type(16)));

typedef __attribute__((address_space(1))) void as1_void_t;
typedef __attribute__((address_space(3))) void as3_void_t;

__device__ __forceinline__ void gload_lds16(const bf16_t* g, bf16_t* l) {
  __builtin_amdgcn_global_load_lds((as1_void_t*)g, (as3_void_t*)l, 16, 0, 0);
}

// ---------------------------------------------------------------------------
// Prep: cast x to bf16; cast+transpose weights (Wt[n][k] = W[k][n]) to bf16.
// ---------------------------------------------------------------------------
__global__ __launch_bounds__(256) void prep_k(
    const float* __restrict__ x,
    const float* __restrict__ wq, const float* __restrict__ wk,
    const float* __restrict__ wv, const float* __restrict__ wo,
    bf16_t* __restrict__ xb, bf16_t* __restrict__ wqt,
    bf16_t* __restrict__ wkt, bf16_t* __restrict__ wvt, bf16_t* __restrict__ wot)
{
  const int stride = gridDim.x * blockDim.x;
  const int tid = blockIdx.x * blockDim.x + threadIdx.x;
  const int NX4 = (8192 * 1024) / 4;
  for (int i = tid; i < NX4; i += stride) {
    float4 v = ((const float4*)x)[i];
    bf16x4 o;
    o[0] = (bf16_t)v.x; o[1] = (bf16_t)v.y; o[2] = (bf16_t)v.z; o[3] = (bf16_t)v.w;
    ((bf16x4*)xb)[i] = o;
  }
  const int NW = 1024 * 1024;
  for (int i = tid; i < NW; i += stride) {
    int k = i >> 10, n = i & 1023;
    int t = n * 1024 + k;
    wqt[t] = (bf16_t)wq[i];
    wkt[t] = (bf16_t)wk[i];
    wvt[t] = (bf16_t)wv[i];
    wot[t] = (bf16_t)wo[i];
  }
}

// ---------------------------------------------------------------------------
// GEMM (unchanged, m97-structure): C[8192][1024] = A * Wt^T, 128x128, BK=64.
// ---------------------------------------------------------------------------
constexpr int BM = 128, BN = 128, BK = 64;

template <int MODE>
__global__ __launch_bounds__(256) void gemm_k(
    const bf16_t* __restrict__ A, const bf16_t* __restrict__ Bt,
    const float* __restrict__ bias, void* __restrict__ outp, float oscale)
{
  constexpr int K = 1024;
  __shared__ bf16_t a_lds[BM * BK];
  __shared__ bf16_t b_lds[BN * BK];
  const int tid = threadIdx.x;
  const int l = tid & 63;
  const int wv = tid >> 6;
  const int wr = wv >> 1, wc = wv & 1;
  const int lr = l & 15, lg = l >> 4;
  const int bm = blockIdx.x * BM;
  const int bn = blockIdx.y * BN;

  f32x4 acc[4][4] = {};

  const int srow = tid >> 3;
  const int scc = tid & 7;

  for (int k0 = 0; k0 < K; k0 += BK) {
    __syncthreads();
#pragma unroll
    for (int it = 0; it < 4; ++it) {
      int row = srow + it * 32;
      int gk = (scc ^ (row & 7)) * 8;
      gload_lds16(A + (size_t)(bm + row) * K + k0 + gk, a_lds + row * BK + scc * 8);
      gload_lds16(Bt + (size_t)(bn + row) * K + k0 + gk, b_lds + row * BK + scc * 8);
    }
    __syncthreads();
#pragma unroll
    for (int kk = 0; kk < 2; ++kk) {
      bf16x8 af[4], bfr[4];
#pragma unroll
      for (int m = 0; m < 4; ++m) {
        int row = wr * 64 + m * 16 + lr;
        int ch = (kk * 4 + lg) ^ (row & 7);
        af[m] = *(const bf16x8*)&a_lds[row * BK + ch * 8];
      }
#pragma unroll
      for (int n = 0; n < 4; ++n) {
        int row = wc * 64 + n * 16 + lr;
        int ch = (kk * 4 + lg) ^ (row & 7);
        bfr[n] = *(const bf16x8*)&b_lds[row * BK + ch * 8];
      }
#pragma unroll
      for (int m = 0; m < 4; ++m)
#pragma unroll
        for (int n = 0; n < 4; ++n)
          acc[m][n] = __builtin_amdgcn_mfma_f32_16x16x32_bf16(af[m], bfr[n], acc[m][n], 0, 0, 0);
    }
  }

#pragma unroll
  for (int m = 0; m < 4; ++m) {
#pragma unroll
    for (int n = 0; n < 4; ++n) {
#pragma unroll
      for (int r = 0; r < 4; ++r) {
        int row = bm + wr * 64 + m * 16 + lg * 4 + r;
        int col = bn + wc * 64 + n * 16 + lr;
        float v = acc[m][n][r] + bias[col];
        if constexpr (MODE == 0) {
          ((bf16_t*)outp)[((size_t)((row >> 11) * 16 + (col >> 6)) * 2048 + (row & 2047)) * 64 + (col & 63)] =
              (bf16_t)(v * oscale);
        } else if constexpr (MODE == 1) {
          ((bf16_t*)outp)[((size_t)((row >> 11) * 16 + (col >> 6)) * 64 + (col & 63)) * 2048 + (row & 2047)] =
              (bf16_t)v;
        } else {
          ((float*)outp)[(size_t)row * 1024 + col] = v;
        }
      }
    }
  }
}

// ---------------------------------------------------------------------------
// Causal flash attention, swapped-operand 32x32x16 structure, no LDS.
// Wave = 32 q rows. S_T = K.Q^T  (lane holds S[kv=crow(r,hi)][q=l&31]),
// softmax lane-local (+1 shfl_xor(32) for cross-half), O^T = V^T.P^T
// (cols = q = l&31 -> alpha/lsum are lane-local scalars).
// Q [BH][S][64] prescaled by 1/8; K [BH][S][64]; V^T [BH][64][S]; all bf16.
// Output bf16 row-major [8192][1024].
// ---------------------------------------------------------------------------
__device__ __forceinline__ unsigned pack2bf(float a, float b) {
  union { bf16_t h[2]; unsigned u; } z;
  z.h[0] = (bf16_t)a; z.h[1] = (bf16_t)b;
  return z.u;
}

__global__ __launch_bounds__(256) void attn_k(
    const bf16_t* __restrict__ Q, const bf16_t* __restrict__ Kmat,
    const bf16_t* __restrict__ Vt, bf16_t* __restrict__ O)
{
  const int S = 2048, HD = 64;
  const int bh = blockIdx.y;
  const int tid = threadIdx.x;
  const int l = tid & 63;
  const int w = tid >> 6;
  const int qt = w * 16 + blockIdx.x;   // striped q-tile assignment (load balance)
  const int qb = qt * 32;
  const int lc = l & 31;
  const int hi = l >> 5;

  const bf16_t* Qh = Q + (size_t)bh * S * HD;
  const bf16_t* Kh = Kmat + (size_t)bh * S * HD;
  const bf16_t* Vh = Vt + (size_t)bh * HD * S;   // [64][2048]

  // Q fragments (B-operand of QK): lane holds Q[qb+lc][d = 16*ds + 8*hi + j]
  bf16x8 qf[4];
#pragma unroll
  for (int ds = 0; ds < 4; ++ds)
    qf[ds] = *(const bf16x8*)&Qh[(size_t)(qb + lc) * HD + ds * 16 + hi * 8];

  float m = -1e30f, lsum = 0.f;
  f32x16 oacc[2] = {};   // O^T[d = crow(r,hi) + 32*dt][q = qb+lc]

  for (int kvb = 0; kvb <= qb; kvb += 32) {
    // ---- S_T tile = K . Q^T ----
    f32x16 st = {};
#pragma unroll
    for (int ds = 0; ds < 4; ++ds) {
      bf16x8 kf = *(const bf16x8*)&Kh[(size_t)(kvb + lc) * HD + ds * 16 + hi * 8];
      st = __builtin_amdgcn_mfma_f32_32x32x16_bf16(kf, qf[ds], st, 0, 0, 0);
    }
    // ---- causal mask: only the diagonal tile ----
    if (kvb == qb) {
#pragma unroll
      for (int r = 0; r < 16; ++r) {
        int kvloc = (r & 3) + 8 * (r >> 2) + 4 * hi;
        if (kvloc > lc) st[r] = -1e30f;
      }
    }
    // ---- online softmax: lane-local 16 + one cross-half shfl ----
    float pmax = st[0];
#pragma unroll
    for (int r = 1; r < 16; ++r) pmax = fmaxf(pmax, st[r]);
    pmax = fmaxf(pmax, __shfl_xor(pmax, 32));
    float mnew = fmaxf(m, pmax);
    float alpha = __expf(m - mnew);
    m = mnew;
    float p[16];
    float s = 0.f;
#pragma unroll
    for (int r = 0; r < 16; ++r) { p[r] = __expf(st[r] - mnew); s += p[r]; }
    s += __shfl_xor(s, 32);
    lsum = lsum * alpha + s;
#pragma unroll
    for (int r = 0; r < 16; ++r) { oacc[0][r] *= alpha; oacc[1][r] *= alpha; }
    // ---- assemble P^T B-fragments (2 ks-slices) in-register ----
    bf16x8 pf[2];
#pragma unroll
    for (int ks = 0; ks < 2; ++ks) {
      unsigned a0 = pack2bf(p[8 * ks + 0], p[8 * ks + 1]);
      unsigned a1 = pack2bf(p[8 * ks + 2], p[8 * ks + 3]);
      unsigned b0 = pack2bf(p[8 * ks + 4], p[8 * ks + 5]);
      unsigned b1 = pack2bf(p[8 * ks + 6], p[8 * ks + 7]);
      unsigned s0 = hi ? a0 : b0;
      unsigned s1 = hi ? a1 : b1;
      unsigned r0 = __shfl_xor(s0, 32);
      unsigned r1 = __shfl_xor(s1, 32);
      union { unsigned wd[4]; bf16x8 v; } z;
      z.wd[0] = hi ? r0 : a0;
      z.wd[1] = hi ? r1 : a1;
      z.wd[2] = hi ? b0 : r0;
      z.wd[3] = hi ? b1 : r1;
      pf[ks] = z.v;
    }
    // ---- O^T += V^T . P^T ----
#pragma unroll
    for (int dt = 0; dt < 2; ++dt) {
#pragma unroll
      for (int ks = 0; ks < 2; ++ks) {
        bf16x8 vf = *(const bf16x8*)&Vh[(size_t)(dt * 32 + lc) * S + kvb + ks * 16 + hi * 8];
        oacc[dt] = __builtin_amdgcn_mfma_f32_32x32x16_bf16(vf, pf[ks], oacc[dt], 0, 0, 0);
      }
    }
  }

  // ---- epilogue: normalize, write bf16 row-major [8192][1024] ----
  const float inv = 1.0f / lsum;
  const int b = bh >> 4, h = bh & 15;
  const size_t rowoff = (size_t)(b * 2048 + qb + lc) * 1024 + h * 64;
#pragma unroll
  for (int dt = 0; dt < 2; ++dt) {
#pragma unroll
    for (int g = 0; g < 4; ++g) {
      bf16x4 o4;
#pragma unroll
      for (int t = 0; t < 4; ++t) o4[t] = (bf16_t)(oacc[dt][g * 4 + t] * inv);
      *(bf16x4*)&O[rowoff + dt * 32 + g * 8 + hi * 4] = o4;
    }
  }
}

// ---------------------------------------------------------------------------
extern "C" void kernel_launch(void* const* d_in, const int* in_sizes, int n_in,
                              void* d_out, int out_size, void* d_ws, size_t ws_size,
                              hipStream_t stream)
{
  (void)in_sizes; (void)n_in; (void)out_size; (void)ws_size;
  const float* x  = (const float*)d_in[0];
  const float* Wq = (const float*)d_in[1];
  const float* bq = (const float*)d_in[2];
  const float* Wk = (const float*)d_in[3];
  const float* bk = (const float*)d_in[4];
  const float* Wv = (const float*)d_in[5];
  const float* bv = (const float*)d_in[6];
  const float* Wo = (const float*)d_in[7];
  const float* bo = (const float*)d_in[8];

  char* ws = (char*)d_ws;
  bf16_t* xb   = (bf16_t*)(ws);                       // 16MB; reused as attn-out
  bf16_t* wqt  = (bf16_t*)(ws + (size_t)(16u << 20));
  bf16_t* wkt  = (bf16_t*)(ws + (size_t)(18u << 20));
  bf16_t* wvt  = (bf16_t*)(ws + (size_t)(20u << 20));
  bf16_t* wot  = (bf16_t*)(ws + (size_t)(22u << 20));
  bf16_t* qws  = (bf16_t*)(ws + (size_t)(24u << 20));
  bf16_t* kws  = (bf16_t*)(ws + (size_t)(40u << 20));
  bf16_t* vtws = (bf16_t*)(ws + (size_t)(56u << 20));

  prep_k<<<2048, 256, 0, stream>>>(x, Wq, Wk, Wv, Wo, xb, wqt, wkt, wvt, wot);

  dim3 gg(8192 / BM, 1024 / BN);
  gemm_k<0><<<gg, 256, 0, stream>>>(xb, wqt, bq, qws, 0.125f);   // Q (scale folded)
  gemm_k<0><<<gg, 256, 0, stream>>>(xb, wkt, bk, kws, 1.0f);     // K
  gemm_k<1><<<gg, 256, 0, stream>>>(xb, wvt, bv, vtws, 1.0f);    // V^T per head

  attn_k<<<dim3(16, 64), 256, 0, stream>>>(qws, kws, vtws, xb);  // out -> xb

  gemm_k<2><<<gg, 256, 0, stream>>>(xb, wot, bo, d_out, 1.0f);   // final, fp32
}

// Round 3
// 253.952 us; speedup vs baseline: 2.2489x; 1.1772x over previous
//
#include <hip/hip_runtime.h>
#include <hip/hip_bf16.h>
#include <cstdint>
#include <cstddef>

typedef __bf16 bf16_t;
typedef __bf16 bf16x4 __attribute__((ext_vector_type(4)));
typedef __bf16 bf16x8 __attribute__((ext_vector_type(8)));
typedef float f32x4 __attribute__((ext_vector_type(4)));
typedef float f32x16 __attribute__((ext_vector_type(16)));

typedef __attribute__((address_space(1))) void as1_void_t;
typedef __attribute__((address_space(3))) void as3_void_t;

__device__ __forceinline__ void gload_lds16(const bf16_t* g, bf16_t* l) {
  __builtin_amdgcn_global_load_lds((as1_void_t*)g, (as3_void_t*)l, 16, 0, 0);
}

// ---------------------------------------------------------------------------
// Prep: cast x to bf16; cast+transpose weights (Wt[n][k] = W[k][n]) to bf16.
// ---------------------------------------------------------------------------
__global__ __launch_bounds__(256) void prep_k(
    const float* __restrict__ x,
    const float* __restrict__ wq, const float* __restrict__ wk,
    const float* __restrict__ wv, const float* __restrict__ wo,
    bf16_t* __restrict__ xb, bf16_t* __restrict__ wqt,
    bf16_t* __restrict__ wkt, bf16_t* __restrict__ wvt, bf16_t* __restrict__ wot)
{
  const int stride = gridDim.x * blockDim.x;
  const int tid = blockIdx.x * blockDim.x + threadIdx.x;
  const int NX4 = (8192 * 1024) / 4;
  for (int i = tid; i < NX4; i += stride) {
    float4 v = ((const float4*)x)[i];
    bf16x4 o;
    o[0] = (bf16_t)v.x; o[1] = (bf16_t)v.y; o[2] = (bf16_t)v.z; o[3] = (bf16_t)v.w;
    ((bf16x4*)xb)[i] = o;
  }
  const int NW = 1024 * 1024;
  for (int i = tid; i < NW; i += stride) {
    int k = i >> 10, n = i & 1023;
    int t = n * 1024 + k;
    wqt[t] = (bf16_t)wq[i];
    wkt[t] = (bf16_t)wk[i];
    wvt[t] = (bf16_t)wv[i];
    wot[t] = (bf16_t)wo[i];
  }
}

// ---------------------------------------------------------------------------
// GEMM (m97-structure): C[8192][1024] = A * Wt^T, 128x128, BK=64.
// ---------------------------------------------------------------------------
constexpr int BM = 128, BN = 128, BK = 64;

template <int MODE>
__global__ __launch_bounds__(256) void gemm_k(
    const bf16_t* __restrict__ A, const bf16_t* __restrict__ Bt,
    const float* __restrict__ bias, void* __restrict__ outp, float oscale)
{
  constexpr int K = 1024;
  __shared__ bf16_t a_lds[BM * BK];
  __shared__ bf16_t b_lds[BN * BK];
  const int tid = threadIdx.x;
  const int l = tid & 63;
  const int wv = tid >> 6;
  const int wr = wv >> 1, wc = wv & 1;
  const int lr = l & 15, lg = l >> 4;
  const int bm = blockIdx.x * BM;
  const int bn = blockIdx.y * BN;

  f32x4 acc[4][4] = {};

  const int srow = tid >> 3;
  const int scc = tid & 7;

  for (int k0 = 0; k0 < K; k0 += BK) {
    __syncthreads();
#pragma unroll
    for (int it = 0; it < 4; ++it) {
      int row = srow + it * 32;
      int gk = (scc ^ (row & 7)) * 8;
      gload_lds16(A + (size_t)(bm + row) * K + k0 + gk, a_lds + row * BK + scc * 8);
      gload_lds16(Bt + (size_t)(bn + row) * K + k0 + gk, b_lds + row * BK + scc * 8);
    }
    __syncthreads();
#pragma unroll
    for (int kk = 0; kk < 2; ++kk) {
      bf16x8 af[4], bfr[4];
#pragma unroll
      for (int m = 0; m < 4; ++m) {
        int row = wr * 64 + m * 16 + lr;
        int ch = (kk * 4 + lg) ^ (row & 7);
        af[m] = *(const bf16x8*)&a_lds[row * BK + ch * 8];
      }
#pragma unroll
      for (int n = 0; n < 4; ++n) {
        int row = wc * 64 + n * 16 + lr;
        int ch = (kk * 4 + lg) ^ (row & 7);
        bfr[n] = *(const bf16x8*)&b_lds[row * BK + ch * 8];
      }
#pragma unroll
      for (int m = 0; m < 4; ++m)
#pragma unroll
        for (int n = 0; n < 4; ++n)
          acc[m][n] = __builtin_amdgcn_mfma_f32_16x16x32_bf16(af[m], bfr[n], acc[m][n], 0, 0, 0);
    }
  }

#pragma unroll
  for (int m = 0; m < 4; ++m) {
#pragma unroll
    for (int n = 0; n < 4; ++n) {
#pragma unroll
      for (int r = 0; r < 4; ++r) {
        int row = bm + wr * 64 + m * 16 + lg * 4 + r;
        int col = bn + wc * 64 + n * 16 + lr;
        float v = acc[m][n][r] + bias[col];
        if constexpr (MODE == 0) {
          ((bf16_t*)outp)[((size_t)((row >> 11) * 16 + (col >> 6)) * 2048 + (row & 2047)) * 64 + (col & 63)] =
              (bf16_t)(v * oscale);
        } else if constexpr (MODE == 1) {
          ((bf16_t*)outp)[((size_t)((row >> 11) * 16 + (col >> 6)) * 64 + (col & 63)) * 2048 + (row & 2047)] =
              (bf16_t)v;
        } else {
          ((float*)outp)[(size_t)row * 1024 + col] = v;
        }
      }
    }
  }
}

// ---------------------------------------------------------------------------
// Causal flash attention, swapped-operand 32x32x16, no LDS.
// Each wave owns TWO q-tiles: qt1 = idx, qt2 = 63-idx  -> every wave does
// exactly 65 tile-computations (perfect balance) and K/V fragment loads are
// shared between the two tiles. Online softmax in exp2 domain (log2e folded
// into Q prescale); defer-max rescale skip (THR=8 log2-units).
// Q [BH][S][64]; K [BH][S][64]; V^T [BH][64][S]; all bf16. Out bf16 [8192][1024].
// ---------------------------------------------------------------------------
__device__ __forceinline__ unsigned pack2bf(float a, float b) {
  union { bf16_t h[2]; unsigned u; } z;
  z.h[0] = (bf16_t)a; z.h[1] = (bf16_t)b;
  return z.u;
}

__device__ __forceinline__ void sm_pv(
    const f32x16& st, const bf16x8 vf[2][2], f32x16 oacc[2],
    float& m, float& lsum, int hi)
{
  float pmax = st[0];
#pragma unroll
  for (int r = 1; r < 16; ++r) pmax = fmaxf(pmax, st[r]);
  pmax = fmaxf(pmax, __shfl_xor(pmax, 32));
  float p[16];
  float s = 0.f;
  if (__any(pmax > m + 8.0f)) {
    float mnew = fmaxf(m, pmax);
    float alpha = __builtin_amdgcn_exp2f(m - mnew);
    m = mnew;
#pragma unroll
    for (int r = 0; r < 16; ++r) { p[r] = __builtin_amdgcn_exp2f(st[r] - mnew); s += p[r]; }
    s += __shfl_xor(s, 32);
    lsum = lsum * alpha + s;
#pragma unroll
    for (int r = 0; r < 16; ++r) { oacc[0][r] *= alpha; oacc[1][r] *= alpha; }
  } else {
#pragma unroll
    for (int r = 0; r < 16; ++r) { p[r] = __builtin_amdgcn_exp2f(st[r] - m); s += p[r]; }
    s += __shfl_xor(s, 32);
    lsum += s;
  }
  // ---- assemble P^T B-fragments (2 k-slices) in-register ----
  bf16x8 pf[2];
#pragma unroll
  for (int ks = 0; ks < 2; ++ks) {
    unsigned a0 = pack2bf(p[8 * ks + 0], p[8 * ks + 1]);
    unsigned a1 = pack2bf(p[8 * ks + 2], p[8 * ks + 3]);
    unsigned b0 = pack2bf(p[8 * ks + 4], p[8 * ks + 5]);
    unsigned b1 = pack2bf(p[8 * ks + 6], p[8 * ks + 7]);
    unsigned s0 = hi ? a0 : b0;
    unsigned s1 = hi ? a1 : b1;
    unsigned r0 = __shfl_xor(s0, 32);
    unsigned r1 = __shfl_xor(s1, 32);
    union { unsigned wd[4]; bf16x8 v; } z;
    z.wd[0] = hi ? r0 : a0;
    z.wd[1] = hi ? r1 : a1;
    z.wd[2] = hi ? b0 : r0;
    z.wd[3] = hi ? b1 : r1;
    pf[ks] = z.v;
  }
#pragma unroll
  for (int dt = 0; dt < 2; ++dt)
#pragma unroll
    for (int ks = 0; ks < 2; ++ks)
      oacc[dt] = __builtin_amdgcn_mfma_f32_32x32x16_bf16(vf[dt][ks], pf[ks], oacc[dt], 0, 0, 0);
}

__global__ __launch_bounds__(256) void attn_k(
    const bf16_t* __restrict__ Q, const bf16_t* __restrict__ Kmat,
    const bf16_t* __restrict__ Vt, bf16_t* __restrict__ O)
{
  const int S = 2048, HD = 64;
  const int bh = blockIdx.x;              // grid (64, 8): same-head blocks -> same XCD
  const int tid = threadIdx.x;
  const int l = tid & 63;
  const int w = tid >> 6;
  const int idx = blockIdx.y * 4 + w;     // 0..31
  const int qt1 = idx, qt2 = 63 - idx;
  const int qb1 = qt1 * 32, qb2 = qt2 * 32;
  const int lc = l & 31;
  const int hi = l >> 5;

  const bf16_t* Qh = Q + (size_t)bh * S * HD;
  const bf16_t* Kh = Kmat + (size_t)bh * S * HD;
  const bf16_t* Vh = Vt + (size_t)bh * HD * S;   // [64][2048]

  bf16x8 qf1[4], qf2[4];
#pragma unroll
  for (int ds = 0; ds < 4; ++ds) {
    qf1[ds] = *(const bf16x8*)&Qh[(size_t)(qb1 + lc) * HD + ds * 16 + hi * 8];
    qf2[ds] = *(const bf16x8*)&Qh[(size_t)(qb2 + lc) * HD + ds * 16 + hi * 8];
  }

  float m1 = -1e30f, ls1 = 0.f, m2 = -1e30f, ls2 = 0.f;
  f32x16 o1[2] = {}, o2[2] = {};

  for (int kvb = 0; kvb <= qb2; kvb += 32) {
    const bool do1 = (kvb <= qb1);
    bf16x8 kf[4];
#pragma unroll
    for (int ds = 0; ds < 4; ++ds)
      kf[ds] = *(const bf16x8*)&Kh[(size_t)(kvb + lc) * HD + ds * 16 + hi * 8];
    // ---- S_T tiles = K . Q^T ----
    f32x16 st2 = {};
#pragma unroll
    for (int ds = 0; ds < 4; ++ds)
      st2 = __builtin_amdgcn_mfma_f32_32x32x16_bf16(kf[ds], qf2[ds], st2, 0, 0, 0);
    f32x16 st1 = {};
    if (do1) {
#pragma unroll
      for (int ds = 0; ds < 4; ++ds)
        st1 = __builtin_amdgcn_mfma_f32_32x32x16_bf16(kf[ds], qf1[ds], st1, 0, 0, 0);
    }
    // ---- causal masks (diagonal tiles only) ----
    if (kvb == qb2) {
#pragma unroll
      for (int r = 0; r < 16; ++r) {
        int kvloc = (r & 3) + 8 * (r >> 2) + 4 * hi;
        if (kvloc > lc) st2[r] = -1e30f;
      }
    }
    if (do1 && kvb == qb1) {
#pragma unroll
      for (int r = 0; r < 16; ++r) {
        int kvloc = (r & 3) + 8 * (r >> 2) + 4 * hi;
        if (kvloc > lc) st1[r] = -1e30f;
      }
    }
    // ---- V fragments (shared) ----
    bf16x8 vf[2][2];
#pragma unroll
    for (int dt = 0; dt < 2; ++dt)
#pragma unroll
      for (int ks = 0; ks < 2; ++ks)
        vf[dt][ks] = *(const bf16x8*)&Vh[(size_t)(dt * 32 + lc) * S + kvb + ks * 16 + hi * 8];
    // ---- softmax + PV per tile ----
    sm_pv(st2, vf, o2, m2, ls2, hi);
    if (do1) sm_pv(st1, vf, o1, m1, ls1, hi);
  }

  // ---- epilogue: normalize, write bf16 row-major [8192][1024] ----
  const int b = bh >> 4, h = bh & 15;
  {
    const float inv = 1.0f / ls1;
    const size_t rowoff = (size_t)(b * 2048 + qb1 + lc) * 1024 + h * 64;
#pragma unroll
    for (int dt = 0; dt < 2; ++dt)
#pragma unroll
      for (int g = 0; g < 4; ++g) {
        bf16x4 o4;
#pragma unroll
        for (int t = 0; t < 4; ++t) o4[t] = (bf16_t)(o1[dt][g * 4 + t] * inv);
        *(bf16x4*)&O[rowoff + dt * 32 + g * 8 + hi * 4] = o4;
      }
  }
  {
    const float inv = 1.0f / ls2;
    const size_t rowoff = (size_t)(b * 2048 + qb2 + lc) * 1024 + h * 64;
#pragma unroll
    for (int dt = 0; dt < 2; ++dt)
#pragma unroll
      for (int g = 0; g < 4; ++g) {
        bf16x4 o4;
#pragma unroll
        for (int t = 0; t < 4; ++t) o4[t] = (bf16_t)(o2[dt][g * 4 + t] * inv);
        *(bf16x4*)&O[rowoff + dt * 32 + g * 8 + hi * 4] = o4;
      }
  }
}

// ---------------------------------------------------------------------------
extern "C" void kernel_launch(void* const* d_in, const int* in_sizes, int n_in,
                              void* d_out, int out_size, void* d_ws, size_t ws_size,
                              hipStream_t stream)
{
  (void)in_sizes; (void)n_in; (void)out_size; (void)ws_size;
  const float* x  = (const float*)d_in[0];
  const float* Wq = (const float*)d_in[1];
  const float* bq = (const float*)d_in[2];
  const float* Wk = (const float*)d_in[3];
  const float* bk = (const float*)d_in[4];
  const float* Wv = (const float*)d_in[5];
  const float* bv = (const float*)d_in[6];
  const float* Wo = (const float*)d_in[7];
  const float* bo = (const float*)d_in[8];

  char* ws = (char*)d_ws;
  bf16_t* xb   = (bf16_t*)(ws);                       // 16MB; reused as attn-out
  bf16_t* wqt  = (bf16_t*)(ws + (size_t)(16u << 20));
  bf16_t* wkt  = (bf16_t*)(ws + (size_t)(18u << 20));
  bf16_t* wvt  = (bf16_t*)(ws + (size_t)(20u << 20));
  bf16_t* wot  = (bf16_t*)(ws + (size_t)(22u << 20));
  bf16_t* qws  = (bf16_t*)(ws + (size_t)(24u << 20));
  bf16_t* kws  = (bf16_t*)(ws + (size_t)(40u << 20));
  bf16_t* vtws = (bf16_t*)(ws + (size_t)(56u << 20));

  prep_k<<<2048, 256, 0, stream>>>(x, Wq, Wk, Wv, Wo, xb, wqt, wkt, wvt, wot);

  dim3 gg(8192 / BM, 1024 / BN);
  // Q scale: 1/sqrt(64) * log2(e)  (attention softmax runs in exp2 domain)
  gemm_k<0><<<gg, 256, 0, stream>>>(xb, wqt, bq, qws, 0.18033688011112042f);
  gemm_k<0><<<gg, 256, 0, stream>>>(xb, wkt, bk, kws, 1.0f);     // K
  gemm_k<1><<<gg, 256, 0, stream>>>(xb, wvt, bv, vtws, 1.0f);    // V^T per head

  attn_k<<<dim3(64, 8), 256, 0, stream>>>(qws, kws, vtws, xb);   // out -> xb

  gemm_k<2><<<gg, 256, 0, stream>>>(xb, wot, bo, d_out, 1.0f);   // final, fp32
}

// Round 6
// 234.337 us; speedup vs baseline: 2.4372x; 1.0837x over previous
//
#include <hip/hip_runtime.h>
#include <hip/hip_bf16.h>
#include <cstdint>
#include <cstddef>

typedef __bf16 bf16_t;
typedef __bf16 bf16x4 __attribute__((ext_vector_type(4)));
typedef __bf16 bf16x8 __attribute__((ext_vector_type(8)));
typedef float f32x4 __attribute__((ext_vector_type(4)));
typedef float f32x16 __attribute__((ext_vector_type(16)));
typedef unsigned u32x2 __attribute__((ext_vector_type(2)));

typedef __attribute__((address_space(1))) void as1_void_t;
typedef __attribute__((address_space(3))) void as3_void_t;

__device__ __forceinline__ void gload_lds16(const bf16_t* g, bf16_t* l) {
  __builtin_amdgcn_global_load_lds((as1_void_t*)g, (as3_void_t*)l, 16, 0, 0);
}

// ---------------------------------------------------------------------------
// Prep: cast x to bf16; cast+transpose weights (Wt[n][k] = W[k][n]) to bf16.
// ---------------------------------------------------------------------------
__global__ __launch_bounds__(256) void prep_k(
    const float* __restrict__ x,
    const float* __restrict__ wq, const float* __restrict__ wk,
    const float* __restrict__ wv, const float* __restrict__ wo,
    bf16_t* __restrict__ xb, bf16_t* __restrict__ wqt,
    bf16_t* __restrict__ wkt, bf16_t* __restrict__ wvt, bf16_t* __restrict__ wot)
{
  const int stride = gridDim.x * blockDim.x;
  const int tid = blockIdx.x * blockDim.x + threadIdx.x;
  const int NX4 = (8192 * 1024) / 4;
  for (int i = tid; i < NX4; i += stride) {
    float4 v = ((const float4*)x)[i];
    bf16x4 o;
    o[0] = (bf16_t)v.x; o[1] = (bf16_t)v.y; o[2] = (bf16_t)v.z; o[3] = (bf16_t)v.w;
    ((bf16x4*)xb)[i] = o;
  }
  const int NW = 1024 * 1024;
  for (int i = tid; i < NW; i += stride) {
    int k = i >> 10, n = i & 1023;
    int t = n * 1024 + k;
    wqt[t] = (bf16_t)wq[i];
    wkt[t] = (bf16_t)wk[i];
    wvt[t] = (bf16_t)wv[i];
    wot[t] = (bf16_t)wo[i];
  }
}

// ---------------------------------------------------------------------------
// Fused QKV GEMM (m97-structure): 128x128 tile, BK=64. blockIdx.z selects
// which projection (0=Q scaled, 1=K, 2=V-transposed).
// ---------------------------------------------------------------------------
constexpr int BM = 128, BN = 128, BK = 64;

__global__ __launch_bounds__(256) void gemm_qkv_k(
    const bf16_t* __restrict__ A,
    const bf16_t* __restrict__ WqT, const bf16_t* __restrict__ WkT,
    const bf16_t* __restrict__ WvT,
    const float* __restrict__ bq, const float* __restrict__ bk,
    const float* __restrict__ bv,
    bf16_t* __restrict__ qo, bf16_t* __restrict__ ko, bf16_t* __restrict__ vo)
{
  constexpr int K = 1024;
  __shared__ bf16_t a_lds[BM * BK];
  __shared__ bf16_t b_lds[BN * BK];
  const int z = blockIdx.z;
  const bf16_t* Bt = (z == 0) ? WqT : (z == 1) ? WkT : WvT;
  const float* bias = (z == 0) ? bq : (z == 1) ? bk : bv;
  bf16_t* outp = (z == 0) ? qo : (z == 1) ? ko : vo;
  // Q scale: 1/sqrt(64) * log2(e)  (softmax runs in exp2 domain)
  const float oscale = (z == 0) ? 0.18033688011112042f : 1.0f;

  const int tid = threadIdx.x;
  const int l = tid & 63;
  const int wv = tid >> 6;
  const int wr = wv >> 1, wc = wv & 1;
  const int lr = l & 15, lg = l >> 4;
  const int bm = blockIdx.x * BM;
  const int bn = blockIdx.y * BN;

  f32x4 acc[4][4] = {};

  const int srow = tid >> 3;
  const int scc = tid & 7;

  for (int k0 = 0; k0 < K; k0 += BK) {
    __syncthreads();
#pragma unroll
    for (int it = 0; it < 4; ++it) {
      int row = srow + it * 32;
      int gk = (scc ^ (row & 7)) * 8;
      gload_lds16(A + (size_t)(bm + row) * K + k0 + gk, a_lds + row * BK + scc * 8);
      gload_lds16(Bt + (size_t)(bn + row) * K + k0 + gk, b_lds + row * BK + scc * 8);
    }
    __syncthreads();
#pragma unroll
    for (int kk = 0; kk < 2; ++kk) {
      bf16x8 af[4], bfr[4];
#pragma unroll
      for (int m = 0; m < 4; ++m) {
        int row = wr * 64 + m * 16 + lr;
        int ch = (kk * 4 + lg) ^ (row & 7);
        af[m] = *(const bf16x8*)&a_lds[row * BK + ch * 8];
      }
#pragma unroll
      for (int n = 0; n < 4; ++n) {
        int row = wc * 64 + n * 16 + lr;
        int ch = (kk * 4 + lg) ^ (row & 7);
        bfr[n] = *(const bf16x8*)&b_lds[row * BK + ch * 8];
      }
#pragma unroll
      for (int m = 0; m < 4; ++m)
#pragma unroll
        for (int n = 0; n < 4; ++n)
          acc[m][n] = __builtin_amdgcn_mfma_f32_16x16x32_bf16(af[m], bfr[n], acc[m][n], 0, 0, 0);
    }
  }

#pragma unroll
  for (int m = 0; m < 4; ++m) {
#pragma unroll
    for (int n = 0; n < 4; ++n) {
#pragma unroll
      for (int r = 0; r < 4; ++r) {
        int row = bm + wr * 64 + m * 16 + lg * 4 + r;
        int col = bn + wc * 64 + n * 16 + lr;
        float v = acc[m][n][r] + bias[col];
        if (z < 2) {   // headsplit [B,H,S,64], scaled
          outp[((size_t)((row >> 11) * 16 + (col >> 6)) * 2048 + (row & 2047)) * 64 + (col & 63)] =
              (bf16_t)(v * oscale);
        } else {       // per-head transposed [B,H,64,S]
          outp[((size_t)((row >> 11) * 16 + (col >> 6)) * 64 + (col & 63)) * 2048 + (row & 2047)] =
              (bf16_t)v;
        }
      }
    }
  }
}

// ---------------------------------------------------------------------------
// Final GEMM: fp32 out = attn_out * Wo^T + bo
// ---------------------------------------------------------------------------
__global__ __launch_bounds__(256) void gemm_o_k(
    const bf16_t* __restrict__ A, const bf16_t* __restrict__ Bt,
    const float* __restrict__ bias, float* __restrict__ outp)
{
  constexpr int K = 1024;
  __shared__ bf16_t a_lds[BM * BK];
  __shared__ bf16_t b_lds[BN * BK];
  const int tid = threadIdx.x;
  const int l = tid & 63;
  const int wv = tid >> 6;
  const int wr = wv >> 1, wc = wv & 1;
  const int lr = l & 15, lg = l >> 4;
  const int bm = blockIdx.x * BM;
  const int bn = blockIdx.y * BN;

  f32x4 acc[4][4] = {};
  const int srow = tid >> 3;
  const int scc = tid & 7;

  for (int k0 = 0; k0 < K; k0 += BK) {
    __syncthreads();
#pragma unroll
    for (int it = 0; it < 4; ++it) {
      int row = srow + it * 32;
      int gk = (scc ^ (row & 7)) * 8;
      gload_lds16(A + (size_t)(bm + row) * K + k0 + gk, a_lds + row * BK + scc * 8);
      gload_lds16(Bt + (size_t)(bn + row) * K + k0 + gk, b_lds + row * BK + scc * 8);
    }
    __syncthreads();
#pragma unroll
    for (int kk = 0; kk < 2; ++kk) {
      bf16x8 af[4], bfr[4];
#pragma unroll
      for (int m = 0; m < 4; ++m) {
        int row = wr * 64 + m * 16 + lr;
        int ch = (kk * 4 + lg) ^ (row & 7);
        af[m] = *(const bf16x8*)&a_lds[row * BK + ch * 8];
      }
#pragma unroll
      for (int n = 0; n < 4; ++n) {
        int row = wc * 64 + n * 16 + lr;
        int ch = (kk * 4 + lg) ^ (row & 7);
        bfr[n] = *(const bf16x8*)&b_lds[row * BK + ch * 8];
      }
#pragma unroll
      for (int m = 0; m < 4; ++m)
#pragma unroll
        for (int n = 0; n < 4; ++n)
          acc[m][n] = __builtin_amdgcn_mfma_f32_16x16x32_bf16(af[m], bfr[n], acc[m][n], 0, 0, 0);
    }
  }

#pragma unroll
  for (int m = 0; m < 4; ++m)
#pragma unroll
    for (int n = 0; n < 4; ++n)
#pragma unroll
      for (int r = 0; r < 4; ++r) {
        int row = bm + wr * 64 + m * 16 + lg * 4 + r;
        int col = bn + wc * 64 + n * 16 + lr;
        outp[(size_t)row * 1024 + col] = acc[m][n][r] + bias[col];
      }
}

// ---------------------------------------------------------------------------
// Causal flash attention, swapped-operand 32x32x16, no LDS.
// Wave owns pair (idx, 63-idx). permlane32_swap (BUILTIN — compiler handles
// the VALU->permlane hazard; raw asm was silently corrupting data) for all
// cross-half traffic, K double-buffer prefetch, max/sum trees, deferred
// half-sum (cross-half add only in epilogue).
// ---------------------------------------------------------------------------
__device__ __forceinline__ unsigned pack2bf(float a, float b) {
  union { bf16_t h[2]; unsigned u; } z;
  z.h[0] = (bf16_t)a; z.h[1] = (bf16_t)b;
  return z.u;
}

// a' = [a.lo | b.lo], b' = [a.hi | b.hi]   (half-swap between two VGPRs)
__device__ __forceinline__ void permswap(unsigned& a, unsigned& b) {
  u32x2 r = __builtin_amdgcn_permlane32_swap(a, b, false, false);
  a = r[0]; b = r[1];
}

__device__ __forceinline__ float xmax32(float x) {
  unsigned a = __float_as_uint(x), b = __float_as_uint(x);
  permswap(a, b);
  return fmaxf(__uint_as_float(a), __uint_as_float(b));
}

__device__ __forceinline__ float xadd32(float x) {
  unsigned a = __float_as_uint(x), b = __float_as_uint(x);
  permswap(a, b);
  return __uint_as_float(a) + __uint_as_float(b);
}

__device__ __forceinline__ void sm_pv(
    const f32x16& st, const bf16x8 vf[2][2], f32x16 oacc[2],
    float& m, float& ls)
{
  // ---- row max: pairwise tree + one cross-half permlane ----
  float u0 = fmaxf(st[0], st[1]),  u1 = fmaxf(st[2], st[3]);
  float u2 = fmaxf(st[4], st[5]),  u3 = fmaxf(st[6], st[7]);
  float u4 = fmaxf(st[8], st[9]),  u5 = fmaxf(st[10], st[11]);
  float u6 = fmaxf(st[12], st[13]), u7 = fmaxf(st[14], st[15]);
  float v0 = fmaxf(u0, u1), v1 = fmaxf(u2, u3), v2 = fmaxf(u4, u5), v3 = fmaxf(u6, u7);
  float pmax = xmax32(fmaxf(fmaxf(v0, v1), fmaxf(v2, v3)));

  float p[16];
  if (__any(pmax > m + 8.0f)) {
    float mnew = fmaxf(m, pmax);
    float alpha = __builtin_amdgcn_exp2f(m - mnew);
    m = mnew;
#pragma unroll
    for (int r = 0; r < 16; ++r) p[r] = __builtin_amdgcn_exp2f(st[r] - mnew);
    float s0 = (p[0] + p[1]) + (p[2] + p[3]);
    float s1 = (p[4] + p[5]) + (p[6] + p[7]);
    float s2 = (p[8] + p[9]) + (p[10] + p[11]);
    float s3 = (p[12] + p[13]) + (p[14] + p[15]);
    ls = ls * alpha + ((s0 + s1) + (s2 + s3));
#pragma unroll
    for (int r = 0; r < 16; ++r) { oacc[0][r] *= alpha; oacc[1][r] *= alpha; }
  } else {
#pragma unroll
    for (int r = 0; r < 16; ++r) p[r] = __builtin_amdgcn_exp2f(st[r] - m);
    float s0 = (p[0] + p[1]) + (p[2] + p[3]);
    float s1 = (p[4] + p[5]) + (p[6] + p[7]);
    float s2 = (p[8] + p[9]) + (p[10] + p[11]);
    float s3 = (p[12] + p[13]) + (p[14] + p[15]);
    ls += ((s0 + s1) + (s2 + s3));
  }

  // ---- P^T B-fragments: 1 permlane pair per k-slice, no selects ----
  bf16x8 pf[2];
#pragma unroll
  for (int ks = 0; ks < 2; ++ks) {
    unsigned a0 = pack2bf(p[8 * ks + 0], p[8 * ks + 1]);
    unsigned a1 = pack2bf(p[8 * ks + 2], p[8 * ks + 3]);
    unsigned b0 = pack2bf(p[8 * ks + 4], p[8 * ks + 5]);
    unsigned b1 = pack2bf(p[8 * ks + 6], p[8 * ks + 7]);
    permswap(a0, b0);   // a0=[a0.lo|b0.lo]=wd0, b0=[a0.hi|b0.hi]=wd2
    permswap(a1, b1);
    union { unsigned wd[4]; bf16x8 v; } zz;
    zz.wd[0] = a0; zz.wd[1] = a1; zz.wd[2] = b0; zz.wd[3] = b1;
    pf[ks] = zz.v;
  }
#pragma unroll
  for (int dt = 0; dt < 2; ++dt)
#pragma unroll
    for (int ks = 0; ks < 2; ++ks)
      oacc[dt] = __builtin_amdgcn_mfma_f32_32x32x16_bf16(vf[dt][ks], pf[ks], oacc[dt], 0, 0, 0);
}

__global__ __launch_bounds__(256) void attn_k(
    const bf16_t* __restrict__ Q, const bf16_t* __restrict__ Kmat,
    const bf16_t* __restrict__ Vt, bf16_t* __restrict__ O)
{
  const int S = 2048, HD = 64;
  const int bh = blockIdx.x;              // grid (64, 8): same-head blocks -> same XCD
  const int tid = threadIdx.x;
  const int l = tid & 63;
  const int w = tid >> 6;
  const int idx = blockIdx.y * 4 + w;     // 0..31
  const int qb1 = idx * 32, qb2 = (63 - idx) * 32;
  const int lc = l & 31;
  const int hi = l >> 5;

  const bf16_t* Qh = Q + (size_t)bh * S * HD;
  const bf16_t* Kh = Kmat + (size_t)bh * S * HD;
  const bf16_t* Vh = Vt + (size_t)bh * HD * S;   // [64][2048]

  bf16x8 qf1[4], qf2[4];
#pragma unroll
  for (int ds = 0; ds < 4; ++ds) {
    qf1[ds] = *(const bf16x8*)&Qh[(size_t)(qb1 + lc) * HD + ds * 16 + hi * 8];
    qf2[ds] = *(const bf16x8*)&Qh[(size_t)(qb2 + lc) * HD + ds * 16 + hi * 8];
  }

  float m1 = -1e30f, ls1 = 0.f, m2 = -1e30f, ls2 = 0.f;
  f32x16 o1[2] = {}, o2[2] = {};

  // ---- one kv-step: V loads early, prefetch next K, QK, mask, sm+PV ----
  auto step = [&](const bf16x8 (&kf)[4], bf16x8 (&kfn)[4], int kvb) {
    bf16x8 vf[2][2];
#pragma unroll
    for (int dt = 0; dt < 2; ++dt)
#pragma unroll
      for (int ks = 0; ks < 2; ++ks)
        vf[dt][ks] = *(const bf16x8*)&Vh[(size_t)(dt * 32 + lc) * S + kvb + ks * 16 + hi * 8];
    const int kvn = (kvb + 32 <= qb2) ? kvb + 32 : kvb;   // clamped prefetch
#pragma unroll
    for (int ds = 0; ds < 4; ++ds)
      kfn[ds] = *(const bf16x8*)&Kh[(size_t)(kvn + lc) * HD + ds * 16 + hi * 8];

    f32x16 st2 = {};
#pragma unroll
    for (int ds = 0; ds < 4; ++ds)
      st2 = __builtin_amdgcn_mfma_f32_32x32x16_bf16(kf[ds], qf2[ds], st2, 0, 0, 0);
    const bool d1 = (kvb <= qb1);
    f32x16 st1 = {};
    if (d1) {
#pragma unroll
      for (int ds = 0; ds < 4; ++ds)
        st1 = __builtin_amdgcn_mfma_f32_32x32x16_bf16(kf[ds], qf1[ds], st1, 0, 0, 0);
    }
    if (kvb == qb2) {
#pragma unroll
      for (int r = 0; r < 16; ++r) {
        int kvloc = (r & 3) + 8 * (r >> 2) + 4 * hi;
        if (kvloc > lc) st2[r] = -1e30f;
      }
    }
    if (d1 && kvb == qb1) {
#pragma unroll
      for (int r = 0; r < 16; ++r) {
        int kvloc = (r & 3) + 8 * (r >> 2) + 4 * hi;
        if (kvloc > lc) st1[r] = -1e30f;
      }
    }
    sm_pv(st2, vf, o2, m2, ls2);
    if (d1) sm_pv(st1, vf, o1, m1, ls1);
  };

  bf16x8 kfA[4], kfB[4];
#pragma unroll
  for (int ds = 0; ds < 4; ++ds)
    kfA[ds] = *(const bf16x8*)&Kh[(size_t)lc * HD + ds * 16 + hi * 8];

  int kvb = 0;
  while (true) {
    step(kfA, kfB, kvb);
    kvb += 32;
    if (kvb > qb2) break;
    step(kfB, kfA, kvb);
    kvb += 32;
    if (kvb > qb2) break;
  }

  // ---- epilogue: cross-half lsum, normalize, write bf16 [8192][1024] ----
  const int b = bh >> 4, h = bh & 15;
  {
    const float inv = 1.0f / xadd32(ls1);
    const size_t rowoff = (size_t)(b * 2048 + qb1 + lc) * 1024 + h * 64;
#pragma unroll
    for (int dt = 0; dt < 2; ++dt)
#pragma unroll
      for (int g = 0; g < 4; ++g) {
        bf16x4 o4;
#pragma unroll
        for (int t = 0; t < 4; ++t) o4[t] = (bf16_t)(o1[dt][g * 4 + t] * inv);
        *(bf16x4*)&O[rowoff + dt * 32 + g * 8 + hi * 4] = o4;
      }
  }
  {
    const float inv = 1.0f / xadd32(ls2);
    const size_t rowoff = (size_t)(b * 2048 + qb2 + lc) * 1024 + h * 64;
#pragma unroll
    for (int dt = 0; dt < 2; ++dt)
#pragma unroll
      for (int g = 0; g < 4; ++g) {
        bf16x4 o4;
#pragma unroll
        for (int t = 0; t < 4; ++t) o4[t] = (bf16_t)(o2[dt][g * 4 + t] * inv);
        *(bf16x4*)&O[rowoff + dt * 32 + g * 8 + hi * 4] = o4;
      }
  }
}

// ---------------------------------------------------------------------------
extern "C" void kernel_launch(void* const* d_in, const int* in_sizes, int n_in,
                              void* d_out, int out_size, void* d_ws, size_t ws_size,
                              hipStream_t stream)
{
  (void)in_sizes; (void)n_in; (void)out_size; (void)ws_size;
  const float* x  = (const float*)d_in[0];
  const float* Wq = (const float*)d_in[1];
  const float* bq = (const float*)d_in[2];
  const float* Wk = (const float*)d_in[3];
  const float* bk = (const float*)d_in[4];
  const float* Wv = (const float*)d_in[5];
  const float* bv = (const float*)d_in[6];
  const float* Wo = (const float*)d_in[7];
  const float* bo = (const float*)d_in[8];

  char* ws = (char*)d_ws;
  bf16_t* xb   = (bf16_t*)(ws);                       // 16MB; reused as attn-out
  bf16_t* wqt  = (bf16_t*)(ws + (size_t)(16u << 20));
  bf16_t* wkt  = (bf16_t*)(ws + (size_t)(18u << 20));
  bf16_t* wvt  = (bf16_t*)(ws + (size_t)(20u << 20));
  bf16_t* wot  = (bf16_t*)(ws + (size_t)(22u << 20));
  bf16_t* qws  = (bf16_t*)(ws + (size_t)(24u << 20));
  bf16_t* kws  = (bf16_t*)(ws + (size_t)(40u << 20));
  bf16_t* vtws = (bf16_t*)(ws + (size_t)(56u << 20));

  prep_k<<<2048, 256, 0, stream>>>(x, Wq, Wk, Wv, Wo, xb, wqt, wkt, wvt, wot);

  dim3 gg(8192 / BM, 1024 / BN, 3);
  gemm_qkv_k<<<gg, 256, 0, stream>>>(xb, wqt, wkt, wvt, bq, bk, bv, qws, kws, vtws);

  attn_k<<<dim3(64, 8), 256, 0, stream>>>(qws, kws, vtws, xb);   // out -> xb

  dim3 go(8192 / BM, 1024 / BN);
  gemm_o_k<<<go, 256, 0, stream>>>(xb, wot, bo, (float*)d_out);
}

// Round 7
// 224.053 us; speedup vs baseline: 2.5490x; 1.0459x over previous
//
#include <hip/hip_runtime.h>
#include <hip/hip_bf16.h>
#include <cstdint>
#include <cstddef>

typedef __bf16 bf16_t;
typedef __bf16 bf16x4 __attribute__((ext_vector_type(4)));
typedef __bf16 bf16x8 __attribute__((ext_vector_type(8)));
typedef float f32x4 __attribute__((ext_vector_type(4)));
typedef float f32x16 __attribute__((ext_vector_type(16)));
typedef unsigned u32x2 __attribute__((ext_vector_type(2)));

typedef __attribute__((address_space(1))) void as1_void_t;
typedef __attribute__((address_space(3))) void as3_void_t;

__device__ __forceinline__ void gload_lds16(const bf16_t* g, bf16_t* l) {
  __builtin_amdgcn_global_load_lds((as1_void_t*)g, (as3_void_t*)l, 16, 0, 0);
}

// ---------------------------------------------------------------------------
// Prep A: cast x to bf16 (vectorized).
// ---------------------------------------------------------------------------
__global__ __launch_bounds__(256) void prep_x_k(
    const float* __restrict__ x, bf16_t* __restrict__ xb)
{
  const int stride = gridDim.x * blockDim.x;
  const int tid = blockIdx.x * blockDim.x + threadIdx.x;
  const int NX4 = (8192 * 1024) / 4;
  for (int i = tid; i < NX4; i += stride) {
    float4 v = ((const float4*)x)[i];
    bf16x4 o;
    o[0] = (bf16_t)v.x; o[1] = (bf16_t)v.y; o[2] = (bf16_t)v.z; o[3] = (bf16_t)v.w;
    ((bf16x4*)xb)[i] = o;
  }
}

// ---------------------------------------------------------------------------
// Prep B: cast+transpose weights via LDS 64x64 tiles (coalesced both sides).
// grid (256 tiles, 4 matrices), block 256.
// ---------------------------------------------------------------------------
__global__ __launch_bounds__(256) void prep_w_k(
    const float* __restrict__ wq, const float* __restrict__ wk,
    const float* __restrict__ wv, const float* __restrict__ wo,
    bf16_t* __restrict__ wqt, bf16_t* __restrict__ wkt,
    bf16_t* __restrict__ wvt, bf16_t* __restrict__ wot)
{
  __shared__ float t[64][65];
  const int zz = blockIdx.y;
  const float* w = (zz == 0) ? wq : (zz == 1) ? wk : (zz == 2) ? wv : wo;
  bf16_t* wt = (zz == 0) ? wqt : (zz == 1) ? wkt : (zz == 2) ? wvt : wot;
  const int tile = blockIdx.x;
  const int tr = tile >> 4, tc = tile & 15;
  const int c = threadIdx.x & 63, r4 = threadIdx.x >> 6;
#pragma unroll
  for (int rr = 0; rr < 16; ++rr) {
    int row = rr * 4 + r4;
    t[row][c] = w[(size_t)(tr * 64 + row) * 1024 + tc * 64 + c];
  }
  __syncthreads();
#pragma unroll
  for (int rr = 0; rr < 16; ++rr) {
    int row = rr * 4 + r4;
    wt[(size_t)(tc * 64 + row) * 1024 + tr * 64 + c] = (bf16_t)t[c][row];
  }
}

// ---------------------------------------------------------------------------
// Fused QKV GEMM (m97-structure): 128x128 tile, BK=64. blockIdx.z selects
// which projection (0=Q scaled, 1=K, 2=V-transposed).
// ---------------------------------------------------------------------------
constexpr int BM = 128, BN = 128, BK = 64;

__global__ __launch_bounds__(256) void gemm_qkv_k(
    const bf16_t* __restrict__ A,
    const bf16_t* __restrict__ WqT, const bf16_t* __restrict__ WkT,
    const bf16_t* __restrict__ WvT,
    const float* __restrict__ bq, const float* __restrict__ bk,
    const float* __restrict__ bv,
    bf16_t* __restrict__ qo, bf16_t* __restrict__ ko, bf16_t* __restrict__ vo)
{
  constexpr int K = 1024;
  __shared__ bf16_t a_lds[BM * BK];
  __shared__ bf16_t b_lds[BN * BK];
  const int z = blockIdx.z;
  const bf16_t* Bt = (z == 0) ? WqT : (z == 1) ? WkT : WvT;
  const float* bias = (z == 0) ? bq : (z == 1) ? bk : bv;
  bf16_t* outp = (z == 0) ? qo : (z == 1) ? ko : vo;
  // Q scale: 1/sqrt(64) * log2(e)  (softmax runs in exp2 domain)
  const float oscale = (z == 0) ? 0.18033688011112042f : 1.0f;

  const int tid = threadIdx.x;
  const int l = tid & 63;
  const int wv = tid >> 6;
  const int wr = wv >> 1, wc = wv & 1;
  const int lr = l & 15, lg = l >> 4;
  const int bm = blockIdx.x * BM;
  const int bn = blockIdx.y * BN;

  f32x4 acc[4][4] = {};

  const int srow = tid >> 3;
  const int scc = tid & 7;

  for (int k0 = 0; k0 < K; k0 += BK) {
    __syncthreads();
#pragma unroll
    for (int it = 0; it < 4; ++it) {
      int row = srow + it * 32;
      int gk = (scc ^ (row & 7)) * 8;
      gload_lds16(A + (size_t)(bm + row) * K + k0 + gk, a_lds + row * BK + scc * 8);
      gload_lds16(Bt + (size_t)(bn + row) * K + k0 + gk, b_lds + row * BK + scc * 8);
    }
    __syncthreads();
#pragma unroll
    for (int kk = 0; kk < 2; ++kk) {
      bf16x8 af[4], bfr[4];
#pragma unroll
      for (int m = 0; m < 4; ++m) {
        int row = wr * 64 + m * 16 + lr;
        int ch = (kk * 4 + lg) ^ (row & 7);
        af[m] = *(const bf16x8*)&a_lds[row * BK + ch * 8];
      }
#pragma unroll
      for (int n = 0; n < 4; ++n) {
        int row = wc * 64 + n * 16 + lr;
        int ch = (kk * 4 + lg) ^ (row & 7);
        bfr[n] = *(const bf16x8*)&b_lds[row * BK + ch * 8];
      }
#pragma unroll
      for (int m = 0; m < 4; ++m)
#pragma unroll
        for (int n = 0; n < 4; ++n)
          acc[m][n] = __builtin_amdgcn_mfma_f32_16x16x32_bf16(af[m], bfr[n], acc[m][n], 0, 0, 0);
    }
  }

#pragma unroll
  for (int m = 0; m < 4; ++m) {
#pragma unroll
    for (int n = 0; n < 4; ++n) {
#pragma unroll
      for (int r = 0; r < 4; ++r) {
        int row = bm + wr * 64 + m * 16 + lg * 4 + r;
        int col = bn + wc * 64 + n * 16 + lr;
        float v = acc[m][n][r] + bias[col];
        if (z < 2) {   // headsplit [B,H,S,64], scaled
          outp[((size_t)((row >> 11) * 16 + (col >> 6)) * 2048 + (row & 2047)) * 64 + (col & 63)] =
              (bf16_t)(v * oscale);
        } else {       // per-head transposed [B,H,64,S]
          outp[((size_t)((row >> 11) * 16 + (col >> 6)) * 64 + (col & 63)) * 2048 + (row & 2047)] =
              (bf16_t)v;
        }
      }
    }
  }
}

// ---------------------------------------------------------------------------
// Final GEMM: fp32 out = attn_out * Wo^T + bo
// ---------------------------------------------------------------------------
__global__ __launch_bounds__(256) void gemm_o_k(
    const bf16_t* __restrict__ A, const bf16_t* __restrict__ Bt,
    const float* __restrict__ bias, float* __restrict__ outp)
{
  constexpr int K = 1024;
  __shared__ bf16_t a_lds[BM * BK];
  __shared__ bf16_t b_lds[BN * BK];
  const int tid = threadIdx.x;
  const int l = tid & 63;
  const int wv = tid >> 6;
  const int wr = wv >> 1, wc = wv & 1;
  const int lr = l & 15, lg = l >> 4;
  const int bm = blockIdx.x * BM;
  const int bn = blockIdx.y * BN;

  f32x4 acc[4][4] = {};
  const int srow = tid >> 3;
  const int scc = tid & 7;

  for (int k0 = 0; k0 < K; k0 += BK) {
    __syncthreads();
#pragma unroll
    for (int it = 0; it < 4; ++it) {
      int row = srow + it * 32;
      int gk = (scc ^ (row & 7)) * 8;
      gload_lds16(A + (size_t)(bm + row) * K + k0 + gk, a_lds + row * BK + scc * 8);
      gload_lds16(Bt + (size_t)(bn + row) * K + k0 + gk, b_lds + row * BK + scc * 8);
    }
    __syncthreads();
#pragma unroll
    for (int kk = 0; kk < 2; ++kk) {
      bf16x8 af[4], bfr[4];
#pragma unroll
      for (int m = 0; m < 4; ++m) {
        int row = wr * 64 + m * 16 + lr;
        int ch = (kk * 4 + lg) ^ (row & 7);
        af[m] = *(const bf16x8*)&a_lds[row * BK + ch * 8];
      }
#pragma unroll
      for (int n = 0; n < 4; ++n) {
        int row = wc * 64 + n * 16 + lr;
        int ch = (kk * 4 + lg) ^ (row & 7);
        bfr[n] = *(const bf16x8*)&b_lds[row * BK + ch * 8];
      }
#pragma unroll
      for (int m = 0; m < 4; ++m)
#pragma unroll
        for (int n = 0; n < 4; ++n)
          acc[m][n] = __builtin_amdgcn_mfma_f32_16x16x32_bf16(af[m], bfr[n], acc[m][n], 0, 0, 0);
    }
  }

#pragma unroll
  for (int m = 0; m < 4; ++m)
#pragma unroll
    for (int n = 0; n < 4; ++n)
#pragma unroll
      for (int r = 0; r < 4; ++r) {
        int row = bm + wr * 64 + m * 16 + lg * 4 + r;
        int col = bn + wc * 64 + n * 16 + lr;
        outp[(size_t)row * 1024 + col] = acc[m][n][r] + bias[col];
      }
}

// ---------------------------------------------------------------------------
// Causal flash attention, swapped-operand 32x32x16.
// Block = 2 waves sharing one q-tile pair (pr, 63-pr); wave h processes
// kv-blocks of parity h (interleaved halves, balanced +-1). Partials merged
// exactly via one LDS exchange. permlane32_swap builtin for cross-half,
// K ping-pong prefetch, max3 trees, deferred half-sum.
// ---------------------------------------------------------------------------
__device__ __forceinline__ unsigned pack2bf(float a, float b) {
  union { bf16_t h[2]; unsigned u; } z;
  z.h[0] = (bf16_t)a; z.h[1] = (bf16_t)b;
  return z.u;
}

// a' = [a.lo | b.lo], b' = [a.hi | b.hi]   (half-swap between two VGPRs)
__device__ __forceinline__ void permswap(unsigned& a, unsigned& b) {
  u32x2 r = __builtin_amdgcn_permlane32_swap(a, b, false, false);
  a = r[0]; b = r[1];
}

__device__ __forceinline__ float xmax32(float x) {
  unsigned a = __float_as_uint(x), b = __float_as_uint(x);
  permswap(a, b);
  return fmaxf(__uint_as_float(a), __uint_as_float(b));
}

__device__ __forceinline__ float xadd32(float x) {
  unsigned a = __float_as_uint(x), b = __float_as_uint(x);
  permswap(a, b);
  return __uint_as_float(a) + __uint_as_float(b);
}

__device__ __forceinline__ float max3f(float a, float b, float c) {
  return fmaxf(fmaxf(a, b), c);
}

__device__ __forceinline__ void sm_pv(
    const f32x16& st, const bf16x8 vf[2][2], f32x16 oacc[2],
    float& m, float& ls)
{
  // ---- row max: max3 tree + one cross-half permlane ----
  float u0 = max3f(st[0], st[1], st[2]);
  float u1 = max3f(st[3], st[4], st[5]);
  float u2 = max3f(st[6], st[7], st[8]);
  float u3 = max3f(st[9], st[10], st[11]);
  float u4 = max3f(st[12], st[13], st[14]);
  float pmax = xmax32(max3f(max3f(u0, u1, u2), max3f(u3, u4, st[15]),
                            -1e30f));

  float p[16];
  if (__any(pmax > m + 8.0f)) {
    float mnew = fmaxf(m, pmax);
    float alpha = __builtin_amdgcn_exp2f(m - mnew);
    m = mnew;
#pragma unroll
    for (int r = 0; r < 16; ++r) p[r] = __builtin_amdgcn_exp2f(st[r] - mnew);
    float s0 = (p[0] + p[1]) + (p[2] + p[3]);
    float s1 = (p[4] + p[5]) + (p[6] + p[7]);
    float s2 = (p[8] + p[9]) + (p[10] + p[11]);
    float s3 = (p[12] + p[13]) + (p[14] + p[15]);
    ls = ls * alpha + ((s0 + s1) + (s2 + s3));
#pragma unroll
    for (int r = 0; r < 16; ++r) { oacc[0][r] *= alpha; oacc[1][r] *= alpha; }
  } else {
#pragma unroll
    for (int r = 0; r < 16; ++r) p[r] = __builtin_amdgcn_exp2f(st[r] - m);
    float s0 = (p[0] + p[1]) + (p[2] + p[3]);
    float s1 = (p[4] + p[5]) + (p[6] + p[7]);
    float s2 = (p[8] + p[9]) + (p[10] + p[11]);
    float s3 = (p[12] + p[13]) + (p[14] + p[15]);
    ls += ((s0 + s1) + (s2 + s3));
  }

  // ---- P^T B-fragments: 1 permlane pair per k-slice ----
  bf16x8 pf[2];
#pragma unroll
  for (int ks = 0; ks < 2; ++ks) {
    unsigned a0 = pack2bf(p[8 * ks + 0], p[8 * ks + 1]);
    unsigned a1 = pack2bf(p[8 * ks + 2], p[8 * ks + 3]);
    unsigned b0 = pack2bf(p[8 * ks + 4], p[8 * ks + 5]);
    unsigned b1 = pack2bf(p[8 * ks + 6], p[8 * ks + 7]);
    permswap(a0, b0);   // a0=[a0.lo|b0.lo]=wd0, b0=[a0.hi|b0.hi]=wd2
    permswap(a1, b1);
    union { unsigned wd[4]; bf16x8 v; } zz;
    zz.wd[0] = a0; zz.wd[1] = a1; zz.wd[2] = b0; zz.wd[3] = b1;
    pf[ks] = zz.v;
  }
#pragma unroll
  for (int dt = 0; dt < 2; ++dt)
#pragma unroll
    for (int ks = 0; ks < 2; ++ks)
      oacc[dt] = __builtin_amdgcn_mfma_f32_32x32x16_bf16(vf[dt][ks], pf[ks], oacc[dt], 0, 0, 0);
}

__global__ __launch_bounds__(128) void attn_k(
    const bf16_t* __restrict__ Q, const bf16_t* __restrict__ Kmat,
    const bf16_t* __restrict__ Vt, bf16_t* __restrict__ O)
{
  const int S = 2048, HD = 64;
  const int bh = blockIdx.x;              // 64; same-head blocks spread evenly
  const int pr = blockIdx.y;              // 0..31 pair index
  const int tid = threadIdx.x;
  const int l = tid & 63;
  const int half = tid >> 6;              // kv-parity this wave owns
  const int qb1 = pr * 32, qb2 = (63 - pr) * 32;
  const int lc = l & 31;
  const int hi = l >> 5;

  __shared__ float mrg[64][71];           // wave-1 partials: 64 O + 2(m,ls)x2

  const bf16_t* Qh = Q + (size_t)bh * S * HD;
  const bf16_t* Kh = Kmat + (size_t)bh * S * HD;
  const bf16_t* Vh = Vt + (size_t)bh * HD * S;   // [64][2048]

  bf16x8 qf1[4], qf2[4];
#pragma unroll
  for (int ds = 0; ds < 4; ++ds) {
    qf1[ds] = *(const bf16x8*)&Qh[(size_t)(qb1 + lc) * HD + ds * 16 + hi * 8];
    qf2[ds] = *(const bf16x8*)&Qh[(size_t)(qb2 + lc) * HD + ds * 16 + hi * 8];
  }

  float m1 = -1e30f, ls1 = 0.f, m2 = -1e30f, ls2 = 0.f;
  f32x16 o1[2] = {}, o2[2] = {};

  // ---- one kv-step: V loads early, prefetch K at +64, QK, mask, sm+PV ----
  auto step = [&](const bf16x8 (&kf)[4], bf16x8 (&kfn)[4], int kvb) {
    bf16x8 vf[2][2];
#pragma unroll
    for (int dt = 0; dt < 2; ++dt)
#pragma unroll
      for (int ks = 0; ks < 2; ++ks)
        vf[dt][ks] = *(const bf16x8*)&Vh[(size_t)(dt * 32 + lc) * S + kvb + ks * 16 + hi * 8];
    const int kvn = (kvb + 64 <= qb2) ? kvb + 64 : kvb;   // clamped prefetch
#pragma unroll
    for (int ds = 0; ds < 4; ++ds)
      kfn[ds] = *(const bf16x8*)&Kh[(size_t)(kvn + lc) * HD + ds * 16 + hi * 8];

    f32x16 st2 = {};
#pragma unroll
    for (int ds = 0; ds < 4; ++ds)
      st2 = __builtin_amdgcn_mfma_f32_32x32x16_bf16(kf[ds], qf2[ds], st2, 0, 0, 0);
    const bool d1 = (kvb <= qb1);
    f32x16 st1 = {};
    if (d1) {
#pragma unroll
      for (int ds = 0; ds < 4; ++ds)
        st1 = __builtin_amdgcn_mfma_f32_32x32x16_bf16(kf[ds], qf1[ds], st1, 0, 0, 0);
    }
    if (kvb == qb2) {
#pragma unroll
      for (int r = 0; r < 16; ++r) {
        int kvloc = (r & 3) + 8 * (r >> 2) + 4 * hi;
        if (kvloc > lc) st2[r] = -1e30f;
      }
    }
    if (d1 && kvb == qb1) {
#pragma unroll
      for (int r = 0; r < 16; ++r) {
        int kvloc = (r & 3) + 8 * (r >> 2) + 4 * hi;
        if (kvloc > lc) st1[r] = -1e30f;
      }
    }
    sm_pv(st2, vf, o2, m2, ls2);
    if (d1) sm_pv(st1, vf, o1, m1, ls1);
  };

  const int kv0 = half * 32;
  bf16x8 kfA[4], kfB[4];
#pragma unroll
  for (int ds = 0; ds < 4; ++ds)
    kfA[ds] = *(const bf16x8*)&Kh[(size_t)(kv0 + lc) * HD + ds * 16 + hi * 8];

  int kvb = kv0;
  while (true) {
    step(kfA, kfB, kvb);
    kvb += 64;
    if (kvb > qb2) break;
    step(kfB, kfA, kvb);
    kvb += 64;
    if (kvb > qb2) break;
  }

  // ---- wave 1 publishes partials ----
  if (half == 1) {
#pragma unroll
    for (int j = 0; j < 16; ++j) {
      mrg[l][j]      = o1[0][j];
      mrg[l][16 + j] = o1[1][j];
      mrg[l][32 + j] = o2[0][j];
      mrg[l][48 + j] = o2[1][j];
    }
    mrg[l][64] = m1; mrg[l][65] = ls1; mrg[l][66] = m2; mrg[l][67] = ls2;
  }
  __syncthreads();

  // ---- wave 0 merges + writes bf16 [8192][1024] ----
  if (half == 0) {
    const int b = bh >> 4, h = bh & 15;
    {
      float mB = mrg[l][64], lsB = mrg[l][65];
      float mm = fmaxf(m1, mB);
      float aA = __builtin_amdgcn_exp2f(m1 - mm);
      float aB = __builtin_amdgcn_exp2f(mB - mm);
      float inv = 1.0f / xadd32(ls1 * aA + lsB * aB);
      const size_t rowoff = (size_t)(b * 2048 + qb1 + lc) * 1024 + h * 64;
#pragma unroll
      for (int dt = 0; dt < 2; ++dt)
#pragma unroll
        for (int g = 0; g < 4; ++g) {
          bf16x4 o4;
#pragma unroll
          for (int t = 0; t < 4; ++t) {
            int j = g * 4 + t;
            o4[t] = (bf16_t)((o1[dt][j] * aA + mrg[l][dt * 16 + j] * aB) * inv);
          }
          *(bf16x4*)&O[rowoff + dt * 32 + g * 8 + hi * 4] = o4;
        }
    }
    {
      float mB = mrg[l][66], lsB = mrg[l][67];
      float mm = fmaxf(m2, mB);
      float aA = __builtin_amdgcn_exp2f(m2 - mm);
      float aB = __builtin_amdgcn_exp2f(mB - mm);
      float inv = 1.0f / xadd32(ls2 * aA + lsB * aB);
      const size_t rowoff = (size_t)(b * 2048 + qb2 + lc) * 1024 + h * 64;
#pragma unroll
      for (int dt = 0; dt < 2; ++dt)
#pragma unroll
        for (int g = 0; g < 4; ++g) {
          bf16x4 o4;
#pragma unroll
          for (int t = 0; t < 4; ++t) {
            int j = g * 4 + t;
            o4[t] = (bf16_t)((o2[dt][j] * aA + mrg[l][32 + dt * 16 + j] * aB) * inv);
          }
          *(bf16x4*)&O[rowoff + dt * 32 + g * 8 + hi * 4] = o4;
        }
    }
  }
}

// ---------------------------------------------------------------------------
extern "C" void kernel_launch(void* const* d_in, const int* in_sizes, int n_in,
                              void* d_out, int out_size, void* d_ws, size_t ws_size,
                              hipStream_t stream)
{
  (void)in_sizes; (void)n_in; (void)out_size; (void)ws_size;
  const float* x  = (const float*)d_in[0];
  const float* Wq = (const float*)d_in[1];
  const float* bq = (const float*)d_in[2];
  const float* Wk = (const float*)d_in[3];
  const float* bk = (const float*)d_in[4];
  const float* Wv = (const float*)d_in[5];
  const float* bv = (const float*)d_in[6];
  const float* Wo = (const float*)d_in[7];
  const float* bo = (const float*)d_in[8];

  char* ws = (char*)d_ws;
  bf16_t* xb   = (bf16_t*)(ws);                       // 16MB; reused as attn-out
  bf16_t* wqt  = (bf16_t*)(ws + (size_t)(16u << 20));
  bf16_t* wkt  = (bf16_t*)(ws + (size_t)(18u << 20));
  bf16_t* wvt  = (bf16_t*)(ws + (size_t)(20u << 20));
  bf16_t* wot  = (bf16_t*)(ws + (size_t)(22u << 20));
  bf16_t* qws  = (bf16_t*)(ws + (size_t)(24u << 20));
  bf16_t* kws  = (bf16_t*)(ws + (size_t)(40u << 20));
  bf16_t* vtws = (bf16_t*)(ws + (size_t)(56u << 20));

  prep_x_k<<<2048, 256, 0, stream>>>(x, xb);
  prep_w_k<<<dim3(256, 4), 256, 0, stream>>>(Wq, Wk, Wv, Wo, wqt, wkt, wvt, wot);

  dim3 gg(8192 / BM, 1024 / BN, 3);
  gemm_qkv_k<<<gg, 256, 0, stream>>>(xb, wqt, wkt, wvt, bq, bk, bv, qws, kws, vtws);

  attn_k<<<dim3(64, 32), 128, 0, stream>>>(qws, kws, vtws, xb);  // out -> xb

  dim3 go(8192 / BM, 1024 / BN);
  gemm_o_k<<<go, 256, 0, stream>>>(xb, wot, bo, (float*)d_out);
}